// Round 21
// baseline (142.521 us; speedup 1.0000x reference)
//
#include <hip/hip_runtime.h>
#include <hip/hip_bf16.h>
#include <stdint.h>

#define BB 32
#define L1 2048
#define L2 512
#define DD 256
#define L2E 1.4426950408889634f
#define NEGS (-1.0e30f * 1.4426950408889634f)

#if __has_builtin(__builtin_amdgcn_exp2f)
#define EXP2(x) __builtin_amdgcn_exp2f(x)
#else
#define EXP2(x) exp2f(x)
#endif

typedef __attribute__((ext_vector_type(4))) float f32x4;
typedef __attribute__((ext_vector_type(8))) short bf16x8;
typedef __attribute__((ext_vector_type(4))) unsigned short u16x4;
typedef __attribute__((ext_vector_type(8))) unsigned short u16x8;

__device__ __forceinline__ unsigned short f2b(float f) {
    union { __hip_bfloat16 h; unsigned short u; } cv;
    cv.h = __float2bfloat16(f);
    return cv.u;
}

// ---- prep: y -> fragment-major bf16 tables + sy = y@w_y (r19 verified) ----
__global__ void prep(const float* __restrict__ y, const float* __restrict__ w_y,
                     unsigned short* __restrict__ ybt, unsigned short* __restrict__ ytt,
                     float* __restrict__ sy) {
    __shared__ float tile[64][264];
    const int tid = threadIdx.x;
    const int lane = tid & 63;
    const int sub = tid >> 6;
    const int b = blockIdx.y;
    const int j0 = blockIdx.x * 64;
    const float* yb = y + ((size_t)b * L2 + j0) * DD;
    f32x4 wv = *(const f32x4*)(w_y + lane * 4);
    #pragma unroll
    for (int p = 0; p < 16; ++p) {
        int row = p * 4 + sub;
        f32x4 v = *(const f32x4*)(yb + (size_t)row * DD + lane * 4);
        *(f32x4*)&tile[row][lane * 4] = v;
        float s = v[0]*wv[0] + v[1]*wv[1] + v[2]*wv[2] + v[3]*wv[3];
        #pragma unroll
        for (int off = 32; off; off >>= 1) s += __shfl_xor(s, off, 64);
        if (lane == 0) sy[b * L2 + j0 + row] = s;
    }
    __syncthreads();
    #pragma unroll
    for (int it = 0; it < 8; ++it) {
        int idx = it * 256 + tid;
        int jt = idx >> 9;
        int rem = idx & 511;
        int kc = rem >> 6;
        int l = rem & 63;
        const float* tr = &tile[jt * 16 + (l & 15)][kc * 32 + (l >> 4) * 8];
        u16x8 pk;
        #pragma unroll
        for (int e = 0; e < 8; ++e) pk[e] = f2b(tr[e]);
        size_t off = (((size_t)b * 32 + blockIdx.x * 4 + jt) * 8 + kc) * 512 + l * 8;
        *(u16x8*)(ybt + off) = pk;
    }
    #pragma unroll
    for (int it = 0; it < 8; ++it) {
        int idx = it * 256 + tid;
        int dt = idx >> 7;
        int rem = idx & 127;
        int kk = rem >> 6;
        int l = rem & 63;
        int c = l & 15, g = l >> 4;
        u16x8 pk;
        #pragma unroll
        for (int e = 0; e < 8; ++e) pk[e] = f2b(tile[kk * 32 + g * 8 + e][dt * 16 + c]);
        size_t off = (((size_t)b * 16 + dt) * 16 + blockIdx.x * 2 + kk) * 512 + l * 8;
        *(u16x8*)(ytt + off) = pk;
    }
}

// ---- main: r19 golden + single-barrier softmax combine + setprio on MFMA ----
__launch_bounds__(256, 2)
__global__ void attn_main(const float* __restrict__ x,
                          const unsigned short* __restrict__ ybt,
                          const unsigned short* __restrict__ ytt,
                          const float* __restrict__ sy,
                          const float* __restrict__ w_x,
                          const float* __restrict__ w_dot,
                          const float* __restrict__ bias,
                          const int* __restrict__ x_mask,
                          const int* __restrict__ y_mask,
                          float* __restrict__ out0,
                          float* __restrict__ out2,
                          float* __restrict__ part,
                          float* __restrict__ MbA,
                          float* __restrict__ SeA) {
    __shared__ __align__(16) unsigned short big[32768];
    __shared__ float sxs[64];
    __shared__ int   xms[64];
    __shared__ float pmax[4][64];
    __shared__ float pz[4][64];

    const int tid = threadIdx.x;
    const int w = tid >> 6;
    const int lane = tid & 63;
    const int g = lane >> 4, c = lane & 15;

    const int wg = blockIdx.x;
    const int slot = wg >> 3;
    const int b = (wg & 7) * 4 + (slot >> 5);
    const int rowblk = slot & 31;
    const int i0 = rowblk * 64;

    // ---- Phase A: xw bf16 -> LDS swizzled; sx folded ----
    {
        const int arow = w * 16 + c;
        const float* xrow = x + ((size_t)(b * L1 + i0 + arow)) * DD;
        float sxpart = 0.f;
        #pragma unroll
        for (int kb = 0; kb < 8; ++kb) {
            int koff = kb * 32 + g * 8;
            f32x4 lo = *(const f32x4*)(xrow + koff);
            f32x4 hi = *(const f32x4*)(xrow + koff + 4);
            f32x4 wdlo = *(const f32x4*)(w_dot + koff);
            f32x4 wdhi = *(const f32x4*)(w_dot + koff + 4);
            f32x4 wxlo = *(const f32x4*)(w_x + koff);
            f32x4 wxhi = *(const f32x4*)(w_x + koff + 4);
            u16x8 a;
            #pragma unroll
            for (int e = 0; e < 4; ++e) {
                a[e]     = f2b(lo[e] * wdlo[e]);
                a[e + 4] = f2b(hi[e] * wdhi[e]);
                sxpart += lo[e] * wxlo[e] + hi[e] * wxhi[e];
            }
            int u = (kb * 4 + g) ^ (c & 7);
            *(u16x8*)((char*)big + arow * 512 + u * 16) = a;
        }
        sxpart += __shfl_xor(sxpart, 16, 64);
        sxpart += __shfl_xor(sxpart, 32, 64);
        if (g == 0) {
            int xmv = x_mask[b * L1 + i0 + arow];
            xms[arow] = xmv;
            sxs[arow] = xmv ? NEGS : (sxpart + bias[0]) * L2E;
        }
    }
    __syncthreads();                                   // B1

    // ---- Phase B: scores (log2-scaled), wave w owns cols [w*128, +128) ----
    f32x4 S[4][8];
    #pragma unroll
    for (int mt = 0; mt < 4; ++mt)
        #pragma unroll
        for (int nt = 0; nt < 8; ++nt) S[mt][nt] = (f32x4){0.f, 0.f, 0.f, 0.f};

    const unsigned short* ybt_b = ybt + (size_t)b * 131072;
    const int col0 = w * 128;
    #pragma unroll 2
    for (int ck = 0; ck < 8; ++ck) {
        bf16x8 bfr[8];
        #pragma unroll
        for (int nt = 0; nt < 8; ++nt)
            bfr[nt] = *(const bf16x8*)(ybt_b + ((size_t)((w * 8 + nt) * 8 + ck) * 512) + lane * 8);
        bf16x8 afr[4];
        #pragma unroll
        for (int mt = 0; mt < 4; ++mt)
            afr[mt] = *(const bf16x8*)((char*)big + (mt * 16 + c) * 512 + ((((ck * 4 + g)) ^ (c & 7)) << 4));
        __builtin_amdgcn_s_setprio(1);
        #pragma unroll
        for (int mt = 0; mt < 4; ++mt)
            #pragma unroll
            for (int nt = 0; nt < 8; ++nt)
                S[mt][nt] = __builtin_amdgcn_mfma_f32_16x16x32_bf16(afr[mt], bfr[nt], S[mt][nt], 0, 0, 0);
        __builtin_amdgcn_s_setprio(0);
    }

    float syt[8];
    #pragma unroll
    for (int nt = 0; nt < 8; ++nt) {
        float sv = sy[b * L2 + col0 + nt * 16 + c];
        int ym = y_mask[b * L2 + col0 + nt * 16 + c];
        syt[nt] = ym ? NEGS : sv * L2E;
    }
    float sxr[4][4]; int xmr[4][4];
    #pragma unroll
    for (int mt = 0; mt < 4; ++mt)
        #pragma unroll
        for (int r = 0; r < 4; ++r) {
            sxr[mt][r] = sxs[mt * 16 + 4 * g + r];
            xmr[mt][r] = xms[mt * 16 + 4 * g + r];
        }
    #pragma unroll
    for (int mt = 0; mt < 4; ++mt)
        #pragma unroll
        for (int nt = 0; nt < 8; ++nt)
            #pragma unroll
            for (int r = 0; r < 4; ++r)
                S[mt][nt][r] = fmaf(S[mt][nt][r], L2E, sxr[mt][r]) + syt[nt];

    // ---- Phase C: softmax, SINGLE barrier (split-max/exp-sum combine) ----
    // per wave: m_w (row partial max over its 128 cols), z_w = sum exp2(S - m_w)
    #pragma unroll
    for (int mt = 0; mt < 4; ++mt)
        #pragma unroll
        for (int r = 0; r < 4; ++r) {
            float pm = S[mt][0][r];
            #pragma unroll
            for (int nt = 1; nt < 8; ++nt) pm = fmaxf(pm, S[mt][nt][r]);
            pm = fmaxf(pm, __shfl_xor(pm, 1, 64));
            pm = fmaxf(pm, __shfl_xor(pm, 2, 64));
            pm = fmaxf(pm, __shfl_xor(pm, 4, 64));
            pm = fmaxf(pm, __shfl_xor(pm, 8, 64));
            // pm now uniform across the 16 lanes of this row
            float zp = 0.f;
            #pragma unroll
            for (int nt = 0; nt < 8; ++nt) {
                float e = EXP2(S[mt][nt][r] - pm);
                S[mt][nt][r] = e;                       // exp2 relative to wave-local max
                zp += e;
            }
            zp += __shfl_xor(zp, 1, 64);
            zp += __shfl_xor(zp, 2, 64);
            zp += __shfl_xor(zp, 4, 64);
            zp += __shfl_xor(zp, 8, 64);
            if (c == 0) {
                pmax[w][mt * 16 + 4 * g + r] = pm;
                pz[w][mt * 16 + 4 * g + r] = zp;
            }
        }
    __syncthreads();                                   // B2 (single softmax barrier)

    float mrow[4][4], scl[4][4], zinv[4][4];
    #pragma unroll
    for (int mt = 0; mt < 4; ++mt)
        #pragma unroll
        for (int r = 0; r < 4; ++r) {
            int row = mt * 16 + 4 * g + r;
            float m0 = pmax[0][row], m1 = pmax[1][row], m2 = pmax[2][row], m3 = pmax[3][row];
            float m = fmaxf(fmaxf(m0, m1), fmaxf(m2, m3));
            float z = pz[0][row] * EXP2(m0 - m) + pz[1][row] * EXP2(m1 - m)
                    + pz[2][row] * EXP2(m2 - m) + pz[3][row] * EXP2(m3 - m);
            mrow[mt][r] = m;
            // this wave's S values are exp2(s - m_w); rescale factor to global max:
            scl[mt][r] = EXP2(pmax[w][row] - m);
            zinv[mt][r] = 1.f / z;
        }

    // beta ingredients (log2 units)
    float Mb;
    {
        float t = mrow[0][0];
        #pragma unroll
        for (int mt = 0; mt < 4; ++mt)
            #pragma unroll
            for (int r = 0; r < 4; ++r) t = fmaxf(t, mrow[mt][r]);
        t = fmaxf(t, __shfl_xor(t, 16, 64));
        t = fmaxf(t, __shfl_xor(t, 32, 64));
        Mb = t;
    }
    float ev[4][4];
    float Se = 0.f;
    #pragma unroll
    for (int mt = 0; mt < 4; ++mt)
        #pragma unroll
        for (int r = 0; r < 4; ++r) {
            ev[mt][r] = EXP2(mrow[mt][r] - Mb);
            Se += ev[mt][r];
        }
    Se += __shfl_xor(Se, 16, 64);
    Se += __shfl_xor(Se, 32, 64);
    if (tid == 0) {
        MbA[b * 32 + rowblk] = Mb;
        SeA[b * 32 + rowblk] = Se;
    }

    // ---- Phase D: alpha (rescaled to global max) -> LDS, granule-swizzled ----
    #pragma unroll
    for (int mt = 0; mt < 4; ++mt)
        #pragma unroll
        for (int nt = 0; nt < 8; ++nt)
            #pragma unroll
            for (int r = 0; r < 4; ++r) {
                int row = mt * 16 + 4 * g + r;
                int col = col0 + nt * 16 + c;
                *(unsigned short*)((char*)big + row * 1024 +
                                   (((col >> 3) ^ (row & 7)) << 4) + (col & 7) * 2)
                    = f2b(S[mt][nt][r] * scl[mt][r]);
            }
    __syncthreads();                                   // B3 (alpha ready; xw dead)

    // ---- Phase E: PV, wave w owns d in [w*64, +64); ytt 1KB-burst loads ----
    f32x4 o[4][4];
    #pragma unroll
    for (int mt = 0; mt < 4; ++mt)
        #pragma unroll
        for (int nt = 0; nt < 4; ++nt) o[mt][nt] = (f32x4){0.f, 0.f, 0.f, 0.f};
    const unsigned short* ytt_b = ytt + (size_t)b * 131072;
    #pragma unroll 4
    for (int kf = 0; kf < 16; ++kf) {
        bf16x8 bv[4];
        #pragma unroll
        for (int nt = 0; nt < 4; ++nt)
            bv[nt] = *(const bf16x8*)(ytt_b + ((size_t)((w * 4 + nt) * 16 + kf) * 512) + lane * 8);
        bf16x8 av[4];
        #pragma unroll
        for (int mt = 0; mt < 4; ++mt)
            av[mt] = *(const bf16x8*)((char*)big + (mt * 16 + c) * 1024 + ((((kf * 4 + g)) ^ (c & 7)) << 4));
        __builtin_amdgcn_s_setprio(1);
        #pragma unroll
        for (int mt = 0; mt < 4; ++mt)
            #pragma unroll
            for (int nt = 0; nt < 4; ++nt)
                o[mt][nt] = __builtin_amdgcn_mfma_f32_16x16x32_bf16(av[mt], bv[nt], o[mt][nt], 0, 0, 0);
        __builtin_amdgcn_s_setprio(0);
    }

    // ---- Phase F: epilogue ----
    const float* xb2 = x + ((size_t)b * L1 + i0) * DD;
    const size_t outb = ((size_t)b * L1 + i0) * DD;
    float eq[4] = {0.f, 0.f, 0.f, 0.f};
    #pragma unroll
    for (int mt = 0; mt < 4; ++mt)
        #pragma unroll
        for (int r = 0; r < 4; ++r) {
            int row = mt * 16 + 4 * g + r;
            float zi = zinv[mt][r];
            float ee = ev[mt][r];
            int xmv = xmr[mt][r];
            #pragma unroll
            for (int nt = 0; nt < 4; ++nt) {
                int d = w * 64 + nt * 16 + c;
                float xv = xb2[(size_t)row * DD + d];
                float cv = xmv ? 0.f : o[mt][nt][r] * zi;
                out0[outb + (size_t)row * DD + d] = cv;
                out2[outb + (size_t)row * DD + d] = xv * cv;
                eq[nt] = fmaf(ee, xv, eq[nt]);
            }
        }
    #pragma unroll
    for (int nt = 0; nt < 4; ++nt) {
        float v = eq[nt];
        v += __shfl_xor(v, 16, 64);
        v += __shfl_xor(v, 32, 64);
        if (g == 0) part[((size_t)(b * 32 + rowblk)) * DD + w * 64 + nt * 16 + c] = v;
    }
}

// ---- combine: beta softmax across 32 row-blocks (log2 units) ----
__global__ void q2c_combine(const float* __restrict__ part, const float* __restrict__ MbA,
                            const float* __restrict__ SeA, float* __restrict__ out1) {
    int b = blockIdx.x, d = threadIdx.x;
    float M = -3.0e38f;
    #pragma unroll
    for (int k = 0; k < 32; ++k) M = fmaxf(M, MbA[b * 32 + k]);
    float Z = 0.f, s = 0.f;
    #pragma unroll 8
    for (int k = 0; k < 32; ++k) {
        float wk = exp2f(MbA[b * 32 + k] - M);
        Z += SeA[b * 32 + k] * wk;
        s += part[((size_t)(b * 32 + k)) * DD + d] * wk;
    }
    out1[b * DD + d] = s / Z;
}

extern "C" void kernel_launch(void* const* d_in, const int* in_sizes, int n_in,
                              void* d_out, int out_size, void* d_ws, size_t ws_size,
                              hipStream_t stream) {
    const float* x = (const float*)d_in[0];
    const float* y = (const float*)d_in[1];
    const int* x_mask = (const int*)d_in[2];
    const int* y_mask = (const int*)d_in[3];
    const float* w_x = (const float*)d_in[4];
    const float* w_y = (const float*)d_in[5];
    const float* w_dot = (const float*)d_in[6];
    const float* bias = (const float*)d_in[7];

    char* ws = (char*)d_ws;
    unsigned short* ybt = (unsigned short*)ws;              //  8,388,608 B
    unsigned short* ytt = (unsigned short*)(ws + 8388608);  //  8,388,608 B
    float* sy   = (float*)(ws + 16777216);                  //     65,536 B
    float* part = (float*)(ws + 16842752);                  //  1,048,576 B
    float* MbA  = (float*)(ws + 17891328);                  //      4,096 B
    float* SeA  = (float*)(ws + 17895424);                  //      4,096 B

    float* out0 = (float*)d_out;                            // c2q   (B,L1,D) f32
    float* out1 = out0 + (size_t)BB * L1 * DD;              // q2c   (B,1,D)  f32
    float* out2 = out1 + (size_t)BB * DD;                   // x*c2q (B,L1,D) f32

    prep<<<dim3(L2 / 64, BB), 256, 0, stream>>>(y, w_y, ybt, ytt, sy);
    attn_main<<<dim3(BB * L1 / 64), 256, 0, stream>>>(x, ybt, ytt, sy, w_x, w_dot, bias,
                                                      x_mask, y_mask, out0, out2,
                                                      part, MbA, SeA);
    q2c_combine<<<dim3(BB), 256, 0, stream>>>(part, MbA, SeA, out1);
}

// Round 22
// 106.717 us; speedup vs baseline: 1.3355x; 1.3355x over previous
//
#include <hip/hip_runtime.h>
#include <hip/hip_bf16.h>
#include <stdint.h>

#define BB 32
#define L1 2048
#define L2 512
#define DD 256
#define L2E 1.4426950408889634f
#define NEGS (-1.0e30f * 1.4426950408889634f)

#if __has_builtin(__builtin_amdgcn_exp2f)
#define EXP2(x) __builtin_amdgcn_exp2f(x)
#else
#define EXP2(x) exp2f(x)
#endif

typedef __attribute__((ext_vector_type(4))) float f32x4;
typedef __attribute__((ext_vector_type(8))) short bf16x8;
typedef __attribute__((ext_vector_type(4))) unsigned short u16x4;
typedef __attribute__((ext_vector_type(8))) unsigned short u16x8;

__device__ __forceinline__ unsigned short f2b(float f) {
    union { __hip_bfloat16 h; unsigned short u; } cv;
    cv.h = __float2bfloat16(f);
    return cv.u;
}

// ---- prep: y -> fragment-major bf16 tables + sy = y@w_y ----
// ybt: per (b, jtile=j/16, kchunk=k/32): 1KB block, elem (lane=g*16+c, e) = y_bf[j0+c][k0+g*8+e]
// ytt: per (b, dtile=d/16, kchunk=j/32): 1KB block, elem (lane=g*16+c, e) = y_bf[j=k0+g*8+e][d0+c]
__global__ void prep(const float* __restrict__ y, const float* __restrict__ w_y,
                     unsigned short* __restrict__ ybt, unsigned short* __restrict__ ytt,
                     float* __restrict__ sy) {
    __shared__ float tile[64][264];
    const int tid = threadIdx.x;
    const int lane = tid & 63;
    const int sub = tid >> 6;
    const int b = blockIdx.y;
    const int j0 = blockIdx.x * 64;
    const float* yb = y + ((size_t)b * L2 + j0) * DD;
    f32x4 wv = *(const f32x4*)(w_y + lane * 4);
    #pragma unroll
    for (int p = 0; p < 16; ++p) {
        int row = p * 4 + sub;
        f32x4 v = *(const f32x4*)(yb + (size_t)row * DD + lane * 4);
        *(f32x4*)&tile[row][lane * 4] = v;
        float s = v[0]*wv[0] + v[1]*wv[1] + v[2]*wv[2] + v[3]*wv[3];
        #pragma unroll
        for (int off = 32; off; off >>= 1) s += __shfl_xor(s, off, 64);
        if (lane == 0) sy[b * L2 + j0 + row] = s;
    }
    __syncthreads();
    // ybt: 4 jtiles x 8 kchunks x 64 lane-chunks = 2048 chunks of 16B
    #pragma unroll
    for (int it = 0; it < 8; ++it) {
        int idx = it * 256 + tid;
        int jt = idx >> 9;
        int rem = idx & 511;
        int kc = rem >> 6;
        int l = rem & 63;
        const float* tr = &tile[jt * 16 + (l & 15)][kc * 32 + (l >> 4) * 8];
        u16x8 pk;
        #pragma unroll
        for (int e = 0; e < 8; ++e) pk[e] = f2b(tr[e]);
        size_t off = (((size_t)b * 32 + blockIdx.x * 4 + jt) * 8 + kc) * 512 + l * 8;
        *(u16x8*)(ybt + off) = pk;
    }
    // ytt: 16 dtiles x 2 kchunks x 64 lane-chunks = 2048 chunks of 16B
    #pragma unroll
    for (int it = 0; it < 8; ++it) {
        int idx = it * 256 + tid;
        int dt = idx >> 7;
        int rem = idx & 127;
        int kk = rem >> 6;
        int l = rem & 63;
        int c = l & 15, g = l >> 4;
        u16x8 pk;
        #pragma unroll
        for (int e = 0; e < 8; ++e) pk[e] = f2b(tile[kk * 32 + g * 8 + e][dt * 16 + c]);
        size_t off = (((size_t)b * 16 + dt) * 16 + blockIdx.x * 2 + kk) * 512 + l * 8;
        *(u16x8*)(ytt + off) = pk;
    }
}

// ---- main fused kernel (r19 golden): r13 structure, fragment-major y loads ----
__launch_bounds__(256, 2)
__global__ void attn_main(const float* __restrict__ x,
                          const unsigned short* __restrict__ ybt,
                          const unsigned short* __restrict__ ytt,
                          const float* __restrict__ sy,
                          const float* __restrict__ w_x,
                          const float* __restrict__ w_dot,
                          const float* __restrict__ bias,
                          const int* __restrict__ x_mask,
                          const int* __restrict__ y_mask,
                          float* __restrict__ out0,
                          float* __restrict__ out2,
                          float* __restrict__ part,
                          float* __restrict__ MbA,
                          float* __restrict__ SeA) {
    __shared__ __align__(16) unsigned short big[32768];
    __shared__ float sxs[64];
    __shared__ int   xms[64];
    __shared__ float pmax[4][64];
    __shared__ float pz[4][64];

    const int tid = threadIdx.x;
    const int w = tid >> 6;
    const int lane = tid & 63;
    const int g = lane >> 4, c = lane & 15;

    const int wg = blockIdx.x;
    const int slot = wg >> 3;
    const int b = (wg & 7) * 4 + (slot >> 5);
    const int rowblk = slot & 31;
    const int i0 = rowblk * 64;

    // ---- Phase A: xw bf16 -> LDS swizzled; sx folded ----
    {
        const int arow = w * 16 + c;
        const float* xrow = x + ((size_t)(b * L1 + i0 + arow)) * DD;
        float sxpart = 0.f;
        #pragma unroll
        for (int kb = 0; kb < 8; ++kb) {
            int koff = kb * 32 + g * 8;
            f32x4 lo = *(const f32x4*)(xrow + koff);
            f32x4 hi = *(const f32x4*)(xrow + koff + 4);
            f32x4 wdlo = *(const f32x4*)(w_dot + koff);
            f32x4 wdhi = *(const f32x4*)(w_dot + koff + 4);
            f32x4 wxlo = *(const f32x4*)(w_x + koff);
            f32x4 wxhi = *(const f32x4*)(w_x + koff + 4);
            u16x8 a;
            #pragma unroll
            for (int e = 0; e < 4; ++e) {
                a[e]     = f2b(lo[e] * wdlo[e]);
                a[e + 4] = f2b(hi[e] * wdhi[e]);
                sxpart += lo[e] * wxlo[e] + hi[e] * wxhi[e];
            }
            int u = (kb * 4 + g) ^ (c & 7);
            *(u16x8*)((char*)big + arow * 512 + u * 16) = a;
        }
        sxpart += __shfl_xor(sxpart, 16, 64);
        sxpart += __shfl_xor(sxpart, 32, 64);
        if (g == 0) {
            int xmv = x_mask[b * L1 + i0 + arow];
            xms[arow] = xmv;
            sxs[arow] = xmv ? NEGS : (sxpart + bias[0]) * L2E;
        }
    }
    __syncthreads();                                   // B1

    // ---- Phase B: scores (log2-scaled), wave w owns cols [w*128, +128) ----
    f32x4 S[4][8];
    #pragma unroll
    for (int mt = 0; mt < 4; ++mt)
        #pragma unroll
        for (int nt = 0; nt < 8; ++nt) S[mt][nt] = (f32x4){0.f, 0.f, 0.f, 0.f};

    const unsigned short* ybt_b = ybt + (size_t)b * 131072;   // 32 jtiles * 8 kc * 512
    const int col0 = w * 128;
    #pragma unroll 2
    for (int ck = 0; ck < 8; ++ck) {
        bf16x8 bfr[8];
        #pragma unroll
        for (int nt = 0; nt < 8; ++nt)
            bfr[nt] = *(const bf16x8*)(ybt_b + ((size_t)((w * 8 + nt) * 8 + ck) * 512) + lane * 8);
        bf16x8 afr[4];
        #pragma unroll
        for (int mt = 0; mt < 4; ++mt)
            afr[mt] = *(const bf16x8*)((char*)big + (mt * 16 + c) * 512 + ((((ck * 4 + g)) ^ (c & 7)) << 4));
        #pragma unroll
        for (int mt = 0; mt < 4; ++mt)
            #pragma unroll
            for (int nt = 0; nt < 8; ++nt)
                S[mt][nt] = __builtin_amdgcn_mfma_f32_16x16x32_bf16(afr[mt], bfr[nt], S[mt][nt], 0, 0, 0);
    }

    float syt[8];
    #pragma unroll
    for (int nt = 0; nt < 8; ++nt) {
        float sv = sy[b * L2 + col0 + nt * 16 + c];
        int ym = y_mask[b * L2 + col0 + nt * 16 + c];
        syt[nt] = ym ? NEGS : sv * L2E;
    }
    float sxr[4][4]; int xmr[4][4];
    #pragma unroll
    for (int mt = 0; mt < 4; ++mt)
        #pragma unroll
        for (int r = 0; r < 4; ++r) {
            sxr[mt][r] = sxs[mt * 16 + 4 * g + r];
            xmr[mt][r] = xms[mt * 16 + 4 * g + r];
        }
    #pragma unroll
    for (int mt = 0; mt < 4; ++mt)
        #pragma unroll
        for (int nt = 0; nt < 8; ++nt)
            #pragma unroll
            for (int r = 0; r < 4; ++r)
                S[mt][nt][r] = fmaf(S[mt][nt][r], L2E, sxr[mt][r]) + syt[nt];

    // ---- Phase C: cross-wave softmax (log2 domain) ----
    #pragma unroll
    for (int mt = 0; mt < 4; ++mt)
        #pragma unroll
        for (int r = 0; r < 4; ++r) {
            float pm = S[mt][0][r];
            #pragma unroll
            for (int nt = 1; nt < 8; ++nt) pm = fmaxf(pm, S[mt][nt][r]);
            pm = fmaxf(pm, __shfl_xor(pm, 1, 64));
            pm = fmaxf(pm, __shfl_xor(pm, 2, 64));
            pm = fmaxf(pm, __shfl_xor(pm, 4, 64));
            pm = fmaxf(pm, __shfl_xor(pm, 8, 64));
            if (c == 0) pmax[w][mt * 16 + 4 * g + r] = pm;
        }
    __syncthreads();                                   // B2
    float mrow[4][4];
    #pragma unroll
    for (int mt = 0; mt < 4; ++mt)
        #pragma unroll
        for (int r = 0; r < 4; ++r) {
            int row = mt * 16 + 4 * g + r;
            mrow[mt][r] = fmaxf(fmaxf(pmax[0][row], pmax[1][row]),
                                fmaxf(pmax[2][row], pmax[3][row]));
        }
    #pragma unroll
    for (int mt = 0; mt < 4; ++mt)
        #pragma unroll
        for (int r = 0; r < 4; ++r) {
            float zp = 0.f;
            #pragma unroll
            for (int nt = 0; nt < 8; ++nt) {
                float e = EXP2(S[mt][nt][r] - mrow[mt][r]);
                S[mt][nt][r] = e;
                zp += e;
            }
            zp += __shfl_xor(zp, 1, 64);
            zp += __shfl_xor(zp, 2, 64);
            zp += __shfl_xor(zp, 4, 64);
            zp += __shfl_xor(zp, 8, 64);
            if (c == 0) pz[w][mt * 16 + 4 * g + r] = zp;
        }
    __syncthreads();                                   // B3
    float zinv[4][4];
    #pragma unroll
    for (int mt = 0; mt < 4; ++mt)
        #pragma unroll
        for (int r = 0; r < 4; ++r) {
            int row = mt * 16 + 4 * g + r;
            zinv[mt][r] = 1.f / ((pz[0][row] + pz[1][row]) + (pz[2][row] + pz[3][row]));
        }

    // beta ingredients (log2 units)
    float Mb;
    {
        float t = mrow[0][0];
        #pragma unroll
        for (int mt = 0; mt < 4; ++mt)
            #pragma unroll
            for (int r = 0; r < 4; ++r) t = fmaxf(t, mrow[mt][r]);
        t = fmaxf(t, __shfl_xor(t, 16, 64));
        t = fmaxf(t, __shfl_xor(t, 32, 64));
        Mb = t;
    }
    float ev[4][4];
    float Se = 0.f;
    #pragma unroll
    for (int mt = 0; mt < 4; ++mt)
        #pragma unroll
        for (int r = 0; r < 4; ++r) {
            ev[mt][r] = EXP2(mrow[mt][r] - Mb);
            Se += ev[mt][r];
        }
    Se += __shfl_xor(Se, 16, 64);
    Se += __shfl_xor(Se, 32, 64);
    if (tid == 0) {
        MbA[b * 32 + rowblk] = Mb;
        SeA[b * 32 + rowblk] = Se;
    }

    // ---- Phase D: alpha -> LDS (overlays xw), granule-swizzled ----
    #pragma unroll
    for (int mt = 0; mt < 4; ++mt)
        #pragma unroll
        for (int nt = 0; nt < 8; ++nt)
            #pragma unroll
            for (int r = 0; r < 4; ++r) {
                int row = mt * 16 + 4 * g + r;
                int col = col0 + nt * 16 + c;
                *(unsigned short*)((char*)big + row * 1024 +
                                   (((col >> 3) ^ (row & 7)) << 4) + (col & 7) * 2)
                    = f2b(S[mt][nt][r]);
            }
    __syncthreads();                                   // B4

    // ---- Phase E: PV, wave w owns d in [w*64, +64); ytt 1KB-burst loads ----
    f32x4 o[4][4];
    #pragma unroll
    for (int mt = 0; mt < 4; ++mt)
        #pragma unroll
        for (int nt = 0; nt < 4; ++nt) o[mt][nt] = (f32x4){0.f, 0.f, 0.f, 0.f};
    const unsigned short* ytt_b = ytt + (size_t)b * 131072;   // 16 dtiles * 16 kc * 512
    #pragma unroll 4
    for (int kf = 0; kf < 16; ++kf) {
        bf16x8 bv[4];
        #pragma unroll
        for (int nt = 0; nt < 4; ++nt)
            bv[nt] = *(const bf16x8*)(ytt_b + ((size_t)((w * 4 + nt) * 16 + kf) * 512) + lane * 8);
        bf16x8 av[4];
        #pragma unroll
        for (int mt = 0; mt < 4; ++mt)
            av[mt] = *(const bf16x8*)((char*)big + (mt * 16 + c) * 1024 + ((((kf * 4 + g)) ^ (c & 7)) << 4));
        #pragma unroll
        for (int mt = 0; mt < 4; ++mt)
            #pragma unroll
            for (int nt = 0; nt < 4; ++nt)
                o[mt][nt] = __builtin_amdgcn_mfma_f32_16x16x32_bf16(av[mt], bv[nt], o[mt][nt], 0, 0, 0);
    }

    // ---- Phase F: epilogue ----
    const float* xb2 = x + ((size_t)b * L1 + i0) * DD;
    const size_t outb = ((size_t)b * L1 + i0) * DD;
    float eq[4] = {0.f, 0.f, 0.f, 0.f};
    #pragma unroll
    for (int mt = 0; mt < 4; ++mt)
        #pragma unroll
        for (int r = 0; r < 4; ++r) {
            int row = mt * 16 + 4 * g + r;
            float zi = zinv[mt][r];
            float ee = ev[mt][r];
            int xmv = xmr[mt][r];
            #pragma unroll
            for (int nt = 0; nt < 4; ++nt) {
                int d = w * 64 + nt * 16 + c;
                float xv = xb2[(size_t)row * DD + d];
                float cv = xmv ? 0.f : o[mt][nt][r] * zi;
                out0[outb + (size_t)row * DD + d] = cv;
                out2[outb + (size_t)row * DD + d] = xv * cv;
                eq[nt] = fmaf(ee, xv, eq[nt]);
            }
        }
    #pragma unroll
    for (int nt = 0; nt < 4; ++nt) {
        float v = eq[nt];
        v += __shfl_xor(v, 16, 64);
        v += __shfl_xor(v, 32, 64);
        if (g == 0) part[((size_t)(b * 32 + rowblk)) * DD + w * 64 + nt * 16 + c] = v;
    }
}

// ---- combine: beta softmax across 32 row-blocks (log2 units) ----
__global__ void q2c_combine(const float* __restrict__ part, const float* __restrict__ MbA,
                            const float* __restrict__ SeA, float* __restrict__ out1) {
    int b = blockIdx.x, d = threadIdx.x;
    float M = -3.0e38f;
    #pragma unroll
    for (int k = 0; k < 32; ++k) M = fmaxf(M, MbA[b * 32 + k]);
    float Z = 0.f, s = 0.f;
    #pragma unroll 8
    for (int k = 0; k < 32; ++k) {
        float wk = exp2f(MbA[b * 32 + k] - M);
        Z += SeA[b * 32 + k] * wk;
        s += part[((size_t)(b * 32 + k)) * DD + d] * wk;
    }
    out1[b * DD + d] = s / Z;
}

extern "C" void kernel_launch(void* const* d_in, const int* in_sizes, int n_in,
                              void* d_out, int out_size, void* d_ws, size_t ws_size,
                              hipStream_t stream) {
    const float* x = (const float*)d_in[0];
    const float* y = (const float*)d_in[1];
    const int* x_mask = (const int*)d_in[2];
    const int* y_mask = (const int*)d_in[3];
    const float* w_x = (const float*)d_in[4];
    const float* w_y = (const float*)d_in[5];
    const float* w_dot = (const float*)d_in[6];
    const float* bias = (const float*)d_in[7];

    char* ws = (char*)d_ws;
    unsigned short* ybt = (unsigned short*)ws;              //  8,388,608 B
    unsigned short* ytt = (unsigned short*)(ws + 8388608);  //  8,388,608 B
    float* sy   = (float*)(ws + 16777216);                  //     65,536 B
    float* part = (float*)(ws + 16842752);                  //  1,048,576 B
    float* MbA  = (float*)(ws + 17891328);                  //      4,096 B
    float* SeA  = (float*)(ws + 17895424);                  //      4,096 B

    float* out0 = (float*)d_out;                            // c2q   (B,L1,D) f32
    float* out1 = out0 + (size_t)BB * L1 * DD;              // q2c   (B,1,D)  f32
    float* out2 = out1 + (size_t)BB * DD;                   // x*c2q (B,L1,D) f32

    prep<<<dim3(L2 / 64, BB), 256, 0, stream>>>(y, w_y, ybt, ytt, sy);
    attn_main<<<dim3(BB * L1 / 64), 256, 0, stream>>>(x, ybt, ytt, sy, w_x, w_dot, bias,
                                                      x_mask, y_mask, out0, out2,
                                                      part, MbA, SeA);
    q2c_combine<<<dim3(BB), 256, 0, stream>>>(part, MbA, SeA, out1);
}

// Round 23
// 100.108 us; speedup vs baseline: 1.4237x; 1.0660x over previous
//
#include <hip/hip_runtime.h>
#include <hip/hip_bf16.h>
#include <stdint.h>

#define BB 32
#define L1 2048
#define L2 512
#define DD 256
#define L2E 1.4426950408889634f
#define NEGS (-1.0e30f * 1.4426950408889634f)

#if __has_builtin(__builtin_amdgcn_exp2f)
#define EXP2(x) __builtin_amdgcn_exp2f(x)
#else
#define EXP2(x) exp2f(x)
#endif

typedef __attribute__((ext_vector_type(4))) float f32x4;
typedef __attribute__((ext_vector_type(8))) short bf16x8;
typedef __attribute__((ext_vector_type(4))) unsigned short u16x4;
typedef __attribute__((ext_vector_type(8))) unsigned short u16x8;

__device__ __forceinline__ unsigned short f2b(float f) {
    union { __hip_bfloat16 h; unsigned short u; } cv;
    cv.h = __float2bfloat16(f);
    return cv.u;
}

// ---- prep: y -> fragment-major bf16 tables + sy = y@w_y (r19 verified) ----
__global__ void prep(const float* __restrict__ y, const float* __restrict__ w_y,
                     unsigned short* __restrict__ ybt, unsigned short* __restrict__ ytt,
                     float* __restrict__ sy) {
    __shared__ float tile[64][264];
    const int tid = threadIdx.x;
    const int lane = tid & 63;
    const int sub = tid >> 6;
    const int b = blockIdx.y;
    const int j0 = blockIdx.x * 64;
    const float* yb = y + ((size_t)b * L2 + j0) * DD;
    f32x4 wv = *(const f32x4*)(w_y + lane * 4);
    #pragma unroll
    for (int p = 0; p < 16; ++p) {
        int row = p * 4 + sub;
        f32x4 v = *(const f32x4*)(yb + (size_t)row * DD + lane * 4);
        *(f32x4*)&tile[row][lane * 4] = v;
        float s = v[0]*wv[0] + v[1]*wv[1] + v[2]*wv[2] + v[3]*wv[3];
        #pragma unroll
        for (int off = 32; off; off >>= 1) s += __shfl_xor(s, off, 64);
        if (lane == 0) sy[b * L2 + j0 + row] = s;
    }
    __syncthreads();
    #pragma unroll
    for (int it = 0; it < 8; ++it) {
        int idx = it * 256 + tid;
        int jt = idx >> 9;
        int rem = idx & 511;
        int kc = rem >> 6;
        int l = rem & 63;
        const float* tr = &tile[jt * 16 + (l & 15)][kc * 32 + (l >> 4) * 8];
        u16x8 pk;
        #pragma unroll
        for (int e = 0; e < 8; ++e) pk[e] = f2b(tr[e]);
        size_t off = (((size_t)b * 32 + blockIdx.x * 4 + jt) * 8 + kc) * 512 + l * 8;
        *(u16x8*)(ybt + off) = pk;
    }
    #pragma unroll
    for (int it = 0; it < 8; ++it) {
        int idx = it * 256 + tid;
        int dt = idx >> 7;
        int rem = idx & 127;
        int kk = rem >> 6;
        int l = rem & 63;
        int c = l & 15, g = l >> 4;
        u16x8 pk;
        #pragma unroll
        for (int e = 0; e < 8; ++e) pk[e] = f2b(tile[kk * 32 + g * 8 + e][dt * 16 + c]);
        size_t off = (((size_t)b * 16 + dt) * 16 + blockIdx.x * 2 + kk) * 512 + l * 8;
        *(u16x8*)(ytt + off) = pk;
    }
}

// ---- main (r22 golden + setprio-only A/B): fragment-major y loads ----
__launch_bounds__(256, 2)
__global__ void attn_main(const float* __restrict__ x,
                          const unsigned short* __restrict__ ybt,
                          const unsigned short* __restrict__ ytt,
                          const float* __restrict__ sy,
                          const float* __restrict__ w_x,
                          const float* __restrict__ w_dot,
                          const float* __restrict__ bias,
                          const int* __restrict__ x_mask,
                          const int* __restrict__ y_mask,
                          float* __restrict__ out0,
                          float* __restrict__ out2,
                          float* __restrict__ part,
                          float* __restrict__ MbA,
                          float* __restrict__ SeA) {
    __shared__ __align__(16) unsigned short big[32768];
    __shared__ float sxs[64];
    __shared__ int   xms[64];
    __shared__ float pmax[4][64];
    __shared__ float pz[4][64];

    const int tid = threadIdx.x;
    const int w = tid >> 6;
    const int lane = tid & 63;
    const int g = lane >> 4, c = lane & 15;

    const int wg = blockIdx.x;
    const int slot = wg >> 3;
    const int b = (wg & 7) * 4 + (slot >> 5);
    const int rowblk = slot & 31;
    const int i0 = rowblk * 64;

    // ---- Phase A: xw bf16 -> LDS swizzled; sx folded ----
    {
        const int arow = w * 16 + c;
        const float* xrow = x + ((size_t)(b * L1 + i0 + arow)) * DD;
        float sxpart = 0.f;
        #pragma unroll
        for (int kb = 0; kb < 8; ++kb) {
            int koff = kb * 32 + g * 8;
            f32x4 lo = *(const f32x4*)(xrow + koff);
            f32x4 hi = *(const f32x4*)(xrow + koff + 4);
            f32x4 wdlo = *(const f32x4*)(w_dot + koff);
            f32x4 wdhi = *(const f32x4*)(w_dot + koff + 4);
            f32x4 wxlo = *(const f32x4*)(w_x + koff);
            f32x4 wxhi = *(const f32x4*)(w_x + koff + 4);
            u16x8 a;
            #pragma unroll
            for (int e = 0; e < 4; ++e) {
                a[e]     = f2b(lo[e] * wdlo[e]);
                a[e + 4] = f2b(hi[e] * wdhi[e]);
                sxpart += lo[e] * wxlo[e] + hi[e] * wxhi[e];
            }
            int u = (kb * 4 + g) ^ (c & 7);
            *(u16x8*)((char*)big + arow * 512 + u * 16) = a;
        }
        sxpart += __shfl_xor(sxpart, 16, 64);
        sxpart += __shfl_xor(sxpart, 32, 64);
        if (g == 0) {
            int xmv = x_mask[b * L1 + i0 + arow];
            xms[arow] = xmv;
            sxs[arow] = xmv ? NEGS : (sxpart + bias[0]) * L2E;
        }
    }
    __syncthreads();                                   // B1

    // ---- Phase B: scores (log2-scaled), wave w owns cols [w*128, +128) ----
    f32x4 S[4][8];
    #pragma unroll
    for (int mt = 0; mt < 4; ++mt)
        #pragma unroll
        for (int nt = 0; nt < 8; ++nt) S[mt][nt] = (f32x4){0.f, 0.f, 0.f, 0.f};

    const unsigned short* ybt_b = ybt + (size_t)b * 131072;
    const int col0 = w * 128;
    #pragma unroll 2
    for (int ck = 0; ck < 8; ++ck) {
        bf16x8 bfr[8];
        #pragma unroll
        for (int nt = 0; nt < 8; ++nt)
            bfr[nt] = *(const bf16x8*)(ybt_b + ((size_t)((w * 8 + nt) * 8 + ck) * 512) + lane * 8);
        bf16x8 afr[4];
        #pragma unroll
        for (int mt = 0; mt < 4; ++mt)
            afr[mt] = *(const bf16x8*)((char*)big + (mt * 16 + c) * 512 + ((((ck * 4 + g)) ^ (c & 7)) << 4));
        __builtin_amdgcn_s_setprio(1);
        #pragma unroll
        for (int mt = 0; mt < 4; ++mt)
            #pragma unroll
            for (int nt = 0; nt < 8; ++nt)
                S[mt][nt] = __builtin_amdgcn_mfma_f32_16x16x32_bf16(afr[mt], bfr[nt], S[mt][nt], 0, 0, 0);
        __builtin_amdgcn_s_setprio(0);
    }

    float syt[8];
    #pragma unroll
    for (int nt = 0; nt < 8; ++nt) {
        float sv = sy[b * L2 + col0 + nt * 16 + c];
        int ym = y_mask[b * L2 + col0 + nt * 16 + c];
        syt[nt] = ym ? NEGS : sv * L2E;
    }
    float sxr[4][4]; int xmr[4][4];
    #pragma unroll
    for (int mt = 0; mt < 4; ++mt)
        #pragma unroll
        for (int r = 0; r < 4; ++r) {
            sxr[mt][r] = sxs[mt * 16 + 4 * g + r];
            xmr[mt][r] = xms[mt * 16 + 4 * g + r];
        }
    #pragma unroll
    for (int mt = 0; mt < 4; ++mt)
        #pragma unroll
        for (int nt = 0; nt < 8; ++nt)
            #pragma unroll
            for (int r = 0; r < 4; ++r)
                S[mt][nt][r] = fmaf(S[mt][nt][r], L2E, sxr[mt][r]) + syt[nt];

    // ---- Phase C: cross-wave softmax (log2 domain) ----
    #pragma unroll
    for (int mt = 0; mt < 4; ++mt)
        #pragma unroll
        for (int r = 0; r < 4; ++r) {
            float pm = S[mt][0][r];
            #pragma unroll
            for (int nt = 1; nt < 8; ++nt) pm = fmaxf(pm, S[mt][nt][r]);
            pm = fmaxf(pm, __shfl_xor(pm, 1, 64));
            pm = fmaxf(pm, __shfl_xor(pm, 2, 64));
            pm = fmaxf(pm, __shfl_xor(pm, 4, 64));
            pm = fmaxf(pm, __shfl_xor(pm, 8, 64));
            if (c == 0) pmax[w][mt * 16 + 4 * g + r] = pm;
        }
    __syncthreads();                                   // B2
    float mrow[4][4];
    #pragma unroll
    for (int mt = 0; mt < 4; ++mt)
        #pragma unroll
        for (int r = 0; r < 4; ++r) {
            int row = mt * 16 + 4 * g + r;
            mrow[mt][r] = fmaxf(fmaxf(pmax[0][row], pmax[1][row]),
                                fmaxf(pmax[2][row], pmax[3][row]));
        }
    #pragma unroll
    for (int mt = 0; mt < 4; ++mt)
        #pragma unroll
        for (int r = 0; r < 4; ++r) {
            float zp = 0.f;
            #pragma unroll
            for (int nt = 0; nt < 8; ++nt) {
                float e = EXP2(S[mt][nt][r] - mrow[mt][r]);
                S[mt][nt][r] = e;
                zp += e;
            }
            zp += __shfl_xor(zp, 1, 64);
            zp += __shfl_xor(zp, 2, 64);
            zp += __shfl_xor(zp, 4, 64);
            zp += __shfl_xor(zp, 8, 64);
            if (c == 0) pz[w][mt * 16 + 4 * g + r] = zp;
        }
    __syncthreads();                                   // B3
    float zinv[4][4];
    #pragma unroll
    for (int mt = 0; mt < 4; ++mt)
        #pragma unroll
        for (int r = 0; r < 4; ++r) {
            int row = mt * 16 + 4 * g + r;
            zinv[mt][r] = 1.f / ((pz[0][row] + pz[1][row]) + (pz[2][row] + pz[3][row]));
        }

    // beta ingredients (log2 units)
    float Mb;
    {
        float t = mrow[0][0];
        #pragma unroll
        for (int mt = 0; mt < 4; ++mt)
            #pragma unroll
            for (int r = 0; r < 4; ++r) t = fmaxf(t, mrow[mt][r]);
        t = fmaxf(t, __shfl_xor(t, 16, 64));
        t = fmaxf(t, __shfl_xor(t, 32, 64));
        Mb = t;
    }
    float ev[4][4];
    float Se = 0.f;
    #pragma unroll
    for (int mt = 0; mt < 4; ++mt)
        #pragma unroll
        for (int r = 0; r < 4; ++r) {
            ev[mt][r] = EXP2(mrow[mt][r] - Mb);
            Se += ev[mt][r];
        }
    Se += __shfl_xor(Se, 16, 64);
    Se += __shfl_xor(Se, 32, 64);
    if (tid == 0) {
        MbA[b * 32 + rowblk] = Mb;
        SeA[b * 32 + rowblk] = Se;
    }

    // ---- Phase D: alpha -> LDS (overlays xw), granule-swizzled ----
    #pragma unroll
    for (int mt = 0; mt < 4; ++mt)
        #pragma unroll
        for (int nt = 0; nt < 8; ++nt)
            #pragma unroll
            for (int r = 0; r < 4; ++r) {
                int row = mt * 16 + 4 * g + r;
                int col = col0 + nt * 16 + c;
                *(unsigned short*)((char*)big + row * 1024 +
                                   (((col >> 3) ^ (row & 7)) << 4) + (col & 7) * 2)
                    = f2b(S[mt][nt][r]);
            }
    __syncthreads();                                   // B4

    // ---- Phase E: PV, wave w owns d in [w*64, +64); ytt 1KB-burst loads ----
    f32x4 o[4][4];
    #pragma unroll
    for (int mt = 0; mt < 4; ++mt)
        #pragma unroll
        for (int nt = 0; nt < 4; ++nt) o[mt][nt] = (f32x4){0.f, 0.f, 0.f, 0.f};
    const unsigned short* ytt_b = ytt + (size_t)b * 131072;
    #pragma unroll 4
    for (int kf = 0; kf < 16; ++kf) {
        bf16x8 bv[4];
        #pragma unroll
        for (int nt = 0; nt < 4; ++nt)
            bv[nt] = *(const bf16x8*)(ytt_b + ((size_t)((w * 4 + nt) * 16 + kf) * 512) + lane * 8);
        bf16x8 av[4];
        #pragma unroll
        for (int mt = 0; mt < 4; ++mt)
            av[mt] = *(const bf16x8*)((char*)big + (mt * 16 + c) * 1024 + ((((kf * 4 + g)) ^ (c & 7)) << 4));
        __builtin_amdgcn_s_setprio(1);
        #pragma unroll
        for (int mt = 0; mt < 4; ++mt)
            #pragma unroll
            for (int nt = 0; nt < 4; ++nt)
                o[mt][nt] = __builtin_amdgcn_mfma_f32_16x16x32_bf16(av[mt], bv[nt], o[mt][nt], 0, 0, 0);
        __builtin_amdgcn_s_setprio(0);
    }

    // ---- Phase F: epilogue ----
    const float* xb2 = x + ((size_t)b * L1 + i0) * DD;
    const size_t outb = ((size_t)b * L1 + i0) * DD;
    float eq[4] = {0.f, 0.f, 0.f, 0.f};
    #pragma unroll
    for (int mt = 0; mt < 4; ++mt)
        #pragma unroll
        for (int r = 0; r < 4; ++r) {
            int row = mt * 16 + 4 * g + r;
            float zi = zinv[mt][r];
            float ee = ev[mt][r];
            int xmv = xmr[mt][r];
            #pragma unroll
            for (int nt = 0; nt < 4; ++nt) {
                int d = w * 64 + nt * 16 + c;
                float xv = xb2[(size_t)row * DD + d];
                float cv = xmv ? 0.f : o[mt][nt][r] * zi;
                out0[outb + (size_t)row * DD + d] = cv;
                out2[outb + (size_t)row * DD + d] = xv * cv;
                eq[nt] = fmaf(ee, xv, eq[nt]);
            }
        }
    #pragma unroll
    for (int nt = 0; nt < 4; ++nt) {
        float v = eq[nt];
        v += __shfl_xor(v, 16, 64);
        v += __shfl_xor(v, 32, 64);
        if (g == 0) part[((size_t)(b * 32 + rowblk)) * DD + w * 64 + nt * 16 + c] = v;
    }
}

// ---- combine: beta softmax across 32 row-blocks (log2 units) ----
__global__ void q2c_combine(const float* __restrict__ part, const float* __restrict__ MbA,
                            const float* __restrict__ SeA, float* __restrict__ out1) {
    int b = blockIdx.x, d = threadIdx.x;
    float M = -3.0e38f;
    #pragma unroll
    for (int k = 0; k < 32; ++k) M = fmaxf(M, MbA[b * 32 + k]);
    float Z = 0.f, s = 0.f;
    #pragma unroll 8
    for (int k = 0; k < 32; ++k) {
        float wk = exp2f(MbA[b * 32 + k] - M);
        Z += SeA[b * 32 + k] * wk;
        s += part[((size_t)(b * 32 + k)) * DD + d] * wk;
    }
    out1[b * DD + d] = s / Z;
}

extern "C" void kernel_launch(void* const* d_in, const int* in_sizes, int n_in,
                              void* d_out, int out_size, void* d_ws, size_t ws_size,
                              hipStream_t stream) {
    const float* x = (const float*)d_in[0];
    const float* y = (const float*)d_in[1];
    const int* x_mask = (const int*)d_in[2];
    const int* y_mask = (const int*)d_in[3];
    const float* w_x = (const float*)d_in[4];
    const float* w_y = (const float*)d_in[5];
    const float* w_dot = (const float*)d_in[6];
    const float* bias = (const float*)d_in[7];

    char* ws = (char*)d_ws;
    unsigned short* ybt = (unsigned short*)ws;              //  8,388,608 B
    unsigned short* ytt = (unsigned short*)(ws + 8388608);  //  8,388,608 B
    float* sy   = (float*)(ws + 16777216);                  //     65,536 B
    float* part = (float*)(ws + 16842752);                  //  1,048,576 B
    float* MbA  = (float*)(ws + 17891328);                  //      4,096 B
    float* SeA  = (float*)(ws + 17895424);                  //      4,096 B

    float* out0 = (float*)d_out;                            // c2q   (B,L1,D) f32
    float* out1 = out0 + (size_t)BB * L1 * DD;              // q2c   (B,1,D)  f32
    float* out2 = out1 + (size_t)BB * DD;                   // x*c2q (B,L1,D) f32

    prep<<<dim3(L2 / 64, BB), 256, 0, stream>>>(y, w_y, ybt, ytt, sy);
    attn_main<<<dim3(BB * L1 / 64), 256, 0, stream>>>(x, ybt, ytt, sy, w_x, w_dot, bias,
                                                      x_mask, y_mask, out0, out2,
                                                      part, MbA, SeA);
    q2c_combine<<<dim3(BB), 256, 0, stream>>>(part, MbA, SeA, out1);
}